// Round 1
// baseline (1093.406 us; speedup 1.0000x reference)
//
#include <hip/hip_runtime.h>
#include <math.h>

// Problem constants (from reference)
constexpr int NN = 50000;
constexpr int EE = 800000;
constexpr int H  = 128;
constexpr int ED = 32;
constexpr int EHD = 32;
constexpr int M1 = 128;
constexpr int M2 = 64;
constexpr float BN_EPS = 1e-5f;

constexpr int TE = 32;   // edges per block
constexpr int TN = 32;   // nodes per block

// ---------------------------------------------------------------------------
// K1: per-node projections  Pd = x@Wd + bm1,  Ps = x@Ws
//     (Wd = Wm1 rows [0,128) — multiplies x[dst]; Ws = rows [128,256) — x[src])
// ---------------------------------------------------------------------------
__global__ __launch_bounds__(256) void proj_kernel(
    const float* __restrict__ x, const float* __restrict__ Wm1,
    const float* __restrict__ bm1,
    float* __restrict__ Pd, float* __restrict__ Ps)
{
    __shared__ float sX[TN][H];
    const int t = threadIdx.x;
    const int nbase = blockIdx.x * TN;

    #pragma unroll
    for (int p = 0; p < 4; ++p) {
        int idx = t + p * 256;            // float4 slot 0..1023
        int row = idx >> 5;
        int col = idx & 31;
        int node = nbase + row; if (node >= NN) node = NN - 1;
        reinterpret_cast<float4*>(&sX[row][0])[col] =
            reinterpret_cast<const float4*>(x + (size_t)node * H)[col];
    }
    __syncthreads();

    const int j  = (t & 63) * 2;
    const int e0 = (t >> 6) * 8;
    float2 ad[8], as2[8];
    #pragma unroll
    for (int e = 0; e < 8; ++e) { ad[e] = make_float2(0.f, 0.f); as2[e] = make_float2(0.f, 0.f); }

    for (int k = 0; k < H; k += 4) {
        float2 wd[4], ws_[4];
        #pragma unroll
        for (int q = 0; q < 4; ++q) {
            wd[q]  = *reinterpret_cast<const float2*>(&Wm1[(size_t)(k + q) * M1 + j]);
            ws_[q] = *reinterpret_cast<const float2*>(&Wm1[(size_t)(H + k + q) * M1 + j]);
        }
        #pragma unroll
        for (int e = 0; e < 8; ++e) {
            const float* xr = &sX[e0 + e][k];
            #pragma unroll
            for (int q = 0; q < 4; ++q) {
                float xv = xr[q];
                ad[e].x  = fmaf(xv, wd[q].x,  ad[e].x);
                ad[e].y  = fmaf(xv, wd[q].y,  ad[e].y);
                as2[e].x = fmaf(xv, ws_[q].x, as2[e].x);
                as2[e].y = fmaf(xv, ws_[q].y, as2[e].y);
            }
        }
    }
    const float2 b = *reinterpret_cast<const float2*>(&bm1[j]);
    #pragma unroll
    for (int e = 0; e < 8; ++e) {
        int node = nbase + e0 + e;
        if (node < NN) {
            *reinterpret_cast<float2*>(&Pd[(size_t)node * H + j]) =
                make_float2(ad[e].x + b.x, ad[e].y + b.y);
            *reinterpret_cast<float2*>(&Ps[(size_t)node * H + j]) = as2[e];
        }
    }
}

// ---------------------------------------------------------------------------
// K2: fused edge pipeline: encoder -> h1 -> h2 -> scatter-add(h2) + deg
// ---------------------------------------------------------------------------
__global__ __launch_bounds__(256) void edge_kernel(
    const float* __restrict__ edge_attr, const int* __restrict__ edge_index,
    const float* __restrict__ We1, const float* __restrict__ be1,
    const float* __restrict__ We2, const float* __restrict__ be2,
    const float* __restrict__ Wm1, const float* __restrict__ Wm2,
    const float* __restrict__ bm2,
    const float* __restrict__ Pd, const float* __restrict__ Ps,
    float* __restrict__ agg2, float* __restrict__ deg)
{
    __shared__ float sA[TE][ED];
    __shared__ float sEHid[TE][EHD];
    __shared__ float sEA[TE][EHD];
    __shared__ float sH1[TE][H];
    __shared__ int   sSrc[TE], sDst[TE];

    const int t = threadIdx.x;
    const size_t ebase = (size_t)blockIdx.x * TE;

    if (t < TE) {
        sSrc[t] = edge_index[ebase + t];        // row 0 = src
        sDst[t] = edge_index[EE + ebase + t];   // row 1 = dst
    }
    // edge_attr tile: 32*32 floats = 256 float4, fully coalesced
    reinterpret_cast<float4*>(&sA[0][0])[t] =
        reinterpret_cast<const float4*>(edge_attr + ebase * ED)[t];
    __syncthreads();

    // phase 2a: encoder layer 1 (relu)
    {
        const int j  = t & 31;
        const int e0 = (t >> 5) * 4;
        float acc[4] = {0.f, 0.f, 0.f, 0.f};
        for (int k = 0; k < ED; k += 4) {
            float w[4];
            #pragma unroll
            for (int q = 0; q < 4; ++q) w[q] = We1[(k + q) * EHD + j];
            #pragma unroll
            for (int e = 0; e < 4; ++e) {
                const float* ar = &sA[e0 + e][k];
                #pragma unroll
                for (int q = 0; q < 4; ++q) acc[e] = fmaf(ar[q], w[q], acc[e]);
            }
        }
        const float b = be1[j];
        #pragma unroll
        for (int e = 0; e < 4; ++e) sEHid[e0 + e][j] = fmaxf(acc[e] + b, 0.f);
    }
    // phase 2b: stage Pd[dst]+Ps[src] into sH1 (bias bm1 already folded into Pd)
    {
        const int e = t >> 3;
        const int c = t & 7;
        const float4* pd = reinterpret_cast<const float4*>(Pd + (size_t)sDst[e] * H);
        const float4* ps = reinterpret_cast<const float4*>(Ps + (size_t)sSrc[e] * H);
        float4* sh = reinterpret_cast<float4*>(&sH1[e][0]);
        #pragma unroll
        for (int p = 0; p < 4; ++p) {
            int idx = c + p * 8;
            float4 a = pd[idx];
            float4 b = ps[idx];
            sh[idx] = make_float4(a.x + b.x, a.y + b.y, a.z + b.z, a.w + b.w);
        }
    }
    __syncthreads();
    // phase 3: encoder layer 2 (no relu)
    {
        const int j  = t & 31;
        const int e0 = (t >> 5) * 4;
        float acc[4] = {0.f, 0.f, 0.f, 0.f};
        for (int k = 0; k < EHD; k += 4) {
            float w[4];
            #pragma unroll
            for (int q = 0; q < 4; ++q) w[q] = We2[(k + q) * EHD + j];
            #pragma unroll
            for (int e = 0; e < 4; ++e) {
                const float* ar = &sEHid[e0 + e][k];
                #pragma unroll
                for (int q = 0; q < 4; ++q) acc[e] = fmaf(ar[q], w[q], acc[e]);
            }
        }
        const float b = be2[j];
        #pragma unroll
        for (int e = 0; e < 4; ++e) sEA[e0 + e][j] = acc[e] + b;
    }
    __syncthreads();
    // phase 4: h1 = relu(sH1 + ea @ We_part)   (in place; per-thread disjoint)
    {
        const int j  = (t & 63) * 2;
        const int e0 = (t >> 6) * 8;
        const float* __restrict__ Wme = Wm1 + (size_t)2 * H * M1;  // rows 256..287
        float2 acc[8];
        #pragma unroll
        for (int e = 0; e < 8; ++e) acc[e] = *reinterpret_cast<const float2*>(&sH1[e0 + e][j]);
        for (int k = 0; k < EHD; k += 4) {
            float2 w[4];
            #pragma unroll
            for (int q = 0; q < 4; ++q)
                w[q] = *reinterpret_cast<const float2*>(&Wme[(size_t)(k + q) * M1 + j]);
            #pragma unroll
            for (int e = 0; e < 8; ++e) {
                const float* ar = &sEA[e0 + e][k];
                #pragma unroll
                for (int q = 0; q < 4; ++q) {
                    acc[e].x = fmaf(ar[q], w[q].x, acc[e].x);
                    acc[e].y = fmaf(ar[q], w[q].y, acc[e].y);
                }
            }
        }
        #pragma unroll
        for (int e = 0; e < 8; ++e) {
            sH1[e0 + e][j]     = fmaxf(acc[e].x, 0.f);
            sH1[e0 + e][j + 1] = fmaxf(acc[e].y, 0.f);
        }
    }
    __syncthreads();
    // phase 5: h2 = relu(sH1@Wm2 + bm2); scatter-add h2 and degree
    {
        const int j  = (t & 31) * 2;
        const int e0 = (t >> 5) * 4;
        float2 acc[4];
        #pragma unroll
        for (int e = 0; e < 4; ++e) acc[e] = make_float2(0.f, 0.f);
        for (int k = 0; k < H; k += 4) {
            float2 w[4];
            #pragma unroll
            for (int q = 0; q < 4; ++q)
                w[q] = *reinterpret_cast<const float2*>(&Wm2[(size_t)(k + q) * M2 + j]);
            #pragma unroll
            for (int e = 0; e < 4; ++e) {
                const float* ar = &sH1[e0 + e][k];
                #pragma unroll
                for (int q = 0; q < 4; ++q) {
                    acc[e].x = fmaf(ar[q], w[q].x, acc[e].x);
                    acc[e].y = fmaf(ar[q], w[q].y, acc[e].y);
                }
            }
        }
        const float2 b = *reinterpret_cast<const float2*>(&bm2[j]);
        #pragma unroll
        for (int e = 0; e < 4; ++e) {
            float v0 = fmaxf(acc[e].x + b.x, 0.f);
            float v1 = fmaxf(acc[e].y + b.y, 0.f);
            float* p = agg2 + (size_t)sDst[e0 + e] * M2 + j;
            atomicAdd(p, v0);
            atomicAdd(p + 1, v1);
        }
    }
    if (t < TE) atomicAdd(&deg[sDst[t]], 1.0f);
}

// ---------------------------------------------------------------------------
// K3: m = agg2@Wm3 + deg*bm3 ; GRU(m, x) ; BN(eval) ; +x
// ---------------------------------------------------------------------------
__global__ __launch_bounds__(256) void node_kernel(
    const float* __restrict__ x, const float* __restrict__ agg2,
    const float* __restrict__ deg,
    const float* __restrict__ Wm3, const float* __restrict__ bm3,
    const float* __restrict__ Wih, const float* __restrict__ bih,
    const float* __restrict__ Whh, const float* __restrict__ bhh,
    const float* __restrict__ gamma, const float* __restrict__ beta,
    const float* __restrict__ rmean, const float* __restrict__ rvar,
    float* __restrict__ out)
{
    __shared__ float sX[TN][H];
    __shared__ float sG[TN][M2];
    __shared__ float sM[TN][H];
    __shared__ float sDeg[TN];

    const int t = threadIdx.x;
    const int nbase = blockIdx.x * TN;

    #pragma unroll
    for (int p = 0; p < 4; ++p) {
        int idx = t + p * 256;
        int row = idx >> 5, col = idx & 31;
        int node = nbase + row; if (node >= NN) node = NN - 1;
        reinterpret_cast<float4*>(&sX[row][0])[col] =
            reinterpret_cast<const float4*>(x + (size_t)node * H)[col];
    }
    #pragma unroll
    for (int p = 0; p < 2; ++p) {
        int idx = t + p * 256;
        int row = idx >> 4, col = idx & 15;
        int node = nbase + row; if (node >= NN) node = NN - 1;
        reinterpret_cast<float4*>(&sG[row][0])[col] =
            reinterpret_cast<const float4*>(agg2 + (size_t)node * M2)[col];
    }
    if (t < TN) {
        int node = nbase + t; if (node >= NN) node = NN - 1;
        sDeg[t] = deg[node];
    }
    __syncthreads();

    // m = sG @ Wm3 + deg * bm3   -> sM
    {
        const int j  = (t & 63) * 2;
        const int e0 = (t >> 6) * 8;
        float2 acc[8];
        #pragma unroll
        for (int e = 0; e < 8; ++e) acc[e] = make_float2(0.f, 0.f);
        for (int k = 0; k < M2; k += 4) {
            float2 w[4];
            #pragma unroll
            for (int q = 0; q < 4; ++q)
                w[q] = *reinterpret_cast<const float2*>(&Wm3[(size_t)(k + q) * H + j]);
            #pragma unroll
            for (int e = 0; e < 8; ++e) {
                const float* gr = &sG[e0 + e][k];
                #pragma unroll
                for (int q = 0; q < 4; ++q) {
                    acc[e].x = fmaf(gr[q], w[q].x, acc[e].x);
                    acc[e].y = fmaf(gr[q], w[q].y, acc[e].y);
                }
            }
        }
        const float2 b = *reinterpret_cast<const float2*>(&bm3[j]);
        #pragma unroll
        for (int e = 0; e < 8; ++e) {
            float d = sDeg[e0 + e];
            sM[e0 + e][j]     = fmaf(d, b.x, acc[e].x);
            sM[e0 + e][j + 1] = fmaf(d, b.y, acc[e].y);
        }
    }
    __syncthreads();

    // GRU + BN + residual
    {
        const int jc = t & 127;
        const int ng = t >> 7;
        const float bir = bih[jc], biz = bih[H + jc], bin_ = bih[2 * H + jc];
        const float bhr = bhh[jc], bhz = bhh[H + jc], bhn = bhh[2 * H + jc];
        const float scale = gamma[jc] * rsqrtf(rvar[jc] + BN_EPS);
        const float rm = rmean[jc], bt = beta[jc];
        for (int pass = 0; pass < 4; ++pass) {
            const int n0 = pass * 8 + ng * 4;
            float ir[4] = {0,0,0,0}, iz[4] = {0,0,0,0}, inn[4] = {0,0,0,0};
            float hr[4] = {0,0,0,0}, hz[4] = {0,0,0,0}, hn[4] = {0,0,0,0};
            for (int k = 0; k < H; k += 4) {
                float wir[4], wiz[4], win_[4], whr[4], whz[4], whn[4];
                #pragma unroll
                for (int q = 0; q < 4; ++q) {
                    const float* wi = Wih + (size_t)(k + q) * 3 * H;
                    const float* wh = Whh + (size_t)(k + q) * 3 * H;
                    wir[q] = wi[jc]; wiz[q] = wi[H + jc]; win_[q] = wi[2 * H + jc];
                    whr[q] = wh[jc]; whz[q] = wh[H + jc]; whn[q] = wh[2 * H + jc];
                }
                #pragma unroll
                for (int i = 0; i < 4; ++i) {
                    const float* mr = &sM[n0 + i][k];
                    const float* xr = &sX[n0 + i][k];
                    #pragma unroll
                    for (int q = 0; q < 4; ++q) {
                        float mv = mr[q], xv = xr[q];
                        ir[i]  = fmaf(mv, wir[q],  ir[i]);
                        iz[i]  = fmaf(mv, wiz[q],  iz[i]);
                        inn[i] = fmaf(mv, win_[q], inn[i]);
                        hr[i]  = fmaf(xv, whr[q],  hr[i]);
                        hz[i]  = fmaf(xv, whz[q],  hz[i]);
                        hn[i]  = fmaf(xv, whn[q],  hn[i]);
                    }
                }
            }
            #pragma unroll
            for (int i = 0; i < 4; ++i) {
                int node = nbase + n0 + i;
                if (node < NN) {
                    float r = 1.f / (1.f + expf(-(ir[i] + bir + hr[i] + bhr)));
                    float z = 1.f / (1.f + expf(-(iz[i] + biz + hz[i] + bhz)));
                    float nn2 = tanhf(inn[i] + bin_ + r * (hn[i] + bhn));
                    float xv = sX[n0 + i][jc];
                    float h  = (1.f - z) * nn2 + z * xv;
                    float hb = (h - rm) * scale + bt;
                    out[(size_t)node * H + jc] = hb + xv;
                }
            }
        }
    }
}

// ---------------------------------------------------------------------------
extern "C" void kernel_launch(void* const* d_in, const int* in_sizes, int n_in,
                              void* d_out, int out_size, void* d_ws, size_t ws_size,
                              hipStream_t stream) {
    const float* x         = (const float*)d_in[0];
    const float* edge_attr = (const float*)d_in[1];
    const int*   edge_idx  = (const int*)d_in[2];
    const float* We1 = (const float*)d_in[3];
    const float* be1 = (const float*)d_in[4];
    const float* We2 = (const float*)d_in[5];
    const float* be2 = (const float*)d_in[6];
    const float* Wm1 = (const float*)d_in[7];
    const float* bm1 = (const float*)d_in[8];
    const float* Wm2 = (const float*)d_in[9];
    const float* bm2 = (const float*)d_in[10];
    const float* Wm3 = (const float*)d_in[11];
    const float* bm3 = (const float*)d_in[12];
    const float* Wih = (const float*)d_in[13];
    const float* bih = (const float*)d_in[14];
    const float* Whh = (const float*)d_in[15];
    const float* bhh = (const float*)d_in[16];
    const float* gamma = (const float*)d_in[17];
    const float* beta  = (const float*)d_in[18];
    const float* rmean = (const float*)d_in[19];
    const float* rvar  = (const float*)d_in[20];
    float* out = (float*)d_out;

    float* ws   = (float*)d_ws;
    float* Pd   = ws;                                 // [N,128]
    float* Ps   = ws + (size_t)NN * H;                // [N,128]
    float* agg2 = ws + (size_t)2 * NN * H;            // [N,64]
    float* deg  = agg2 + (size_t)NN * M2;             // [N]

    // zero the accumulation buffers (ws is poisoned before every call)
    hipMemsetAsync(agg2, 0, (size_t)NN * (M2 + 1) * sizeof(float), stream);

    proj_kernel<<<(NN + TN - 1) / TN, 256, 0, stream>>>(x, Wm1, bm1, Pd, Ps);
    edge_kernel<<<EE / TE, 256, 0, stream>>>(edge_attr, edge_idx,
                                             We1, be1, We2, be2,
                                             Wm1, Wm2, bm2, Pd, Ps, agg2, deg);
    node_kernel<<<(NN + TN - 1) / TN, 256, 0, stream>>>(x, agg2, deg,
                                                        Wm3, bm3, Wih, bih, Whh, bhh,
                                                        gamma, beta, rmean, rvar, out);
}

// Round 3
// 767.894 us; speedup vs baseline: 1.4239x; 1.4239x over previous
//
#include <hip/hip_runtime.h>
#include <math.h>

// Problem constants (from reference)
constexpr int NN = 50000;
constexpr int EE = 800000;
constexpr int H  = 128;
constexpr int ED = 32;
constexpr int EHD = 32;
constexpr int M1 = 128;
constexpr int M2 = 64;
constexpr float BN_EPS = 1e-5f;

constexpr int TE = 64;   // edges per block
constexpr int TN = 32;   // nodes per block

typedef __bf16 bf16x8 __attribute__((ext_vector_type(8)));
typedef float  f32x16 __attribute__((ext_vector_type(16)));

static __device__ __forceinline__ f32x16 MFMA(bf16x8 a, bf16x8 b, f32x16 c) {
    return __builtin_amdgcn_mfma_f32_32x32x16_bf16(a, b, c, 0, 0, 0);
}

// ---------------------------------------------------------------------------
// K0: split weights into bf16 hi/lo pairs, pre-swizzled into MFMA B-fragment
// order.  frag layout: B[k = s*16 + (lane>>5)*8 + e][n = nt*32 + (lane&31)]
// stored at ((nt*NS + s)*64 + lane)*8 + e.
// ---------------------------------------------------------------------------
__global__ void pack_weights_kernel(const float* __restrict__ Wm1,
                                    const float* __restrict__ Wm2,
                                    __bf16* __restrict__ w1h, __bf16* __restrict__ w1l,
                                    __bf16* __restrict__ w2h, __bf16* __restrict__ w2l)
{
    int t = blockIdx.x * blockDim.x + threadIdx.x;
    if (t < 4096) {  // Wm1 edge-part: rows 256..287 (32x128): nt(4) x s(2) x lane(64) x e(8)
        int e = t & 7, l = (t >> 3) & 63, s = (t >> 9) & 1, nt = t >> 10;
        int k = s * 16 + (l >> 5) * 8 + e;
        int n = nt * 32 + (l & 31);
        float w = Wm1[(size_t)(2 * H + k) * M1 + n];
        __bf16 hi = (__bf16)w;
        w1h[t] = hi;
        w1l[t] = (__bf16)(w - (float)hi);
    }
    if (t < 8192) {  // Wm2 (128x64): nt(2) x s(8) x lane(64) x e(8)
        int e = t & 7, l = (t >> 3) & 63, s = (t >> 9) & 7, nt = t >> 12;
        int k = s * 16 + (l >> 5) * 8 + e;
        int n = nt * 32 + (l & 31);
        float w = Wm2[(size_t)k * M2 + n];
        __bf16 hi = (__bf16)w;
        w2h[t] = hi;
        w2l[t] = (__bf16)(w - (float)hi);
    }
}

// ---------------------------------------------------------------------------
// K1: per-node projections  Pd = x@Wd + bm1,  Ps = x@Ws
//     (Wd = Wm1 rows [0,128) — multiplies x[dst]; Ws = rows [128,256) — x[src])
// ---------------------------------------------------------------------------
__global__ __launch_bounds__(256) void proj_kernel(
    const float* __restrict__ x, const float* __restrict__ Wm1,
    const float* __restrict__ bm1,
    float* __restrict__ Pd, float* __restrict__ Ps)
{
    __shared__ __align__(16) float sX[TN][H];
    const int t = threadIdx.x;
    const int nbase = blockIdx.x * TN;

    #pragma unroll
    for (int p = 0; p < 4; ++p) {
        int idx = t + p * 256;
        int row = idx >> 5, col = idx & 31;
        int node = nbase + row; if (node >= NN) node = NN - 1;
        reinterpret_cast<float4*>(&sX[row][0])[col] =
            reinterpret_cast<const float4*>(x + (size_t)node * H)[col];
    }
    __syncthreads();

    const int j  = (t & 63) * 2;
    const int e0 = (t >> 6) * 8;
    float2 ad[8], as2[8];
    #pragma unroll
    for (int e = 0; e < 8; ++e) { ad[e] = make_float2(0.f, 0.f); as2[e] = make_float2(0.f, 0.f); }

    for (int k = 0; k < H; k += 4) {
        float2 wd[4], ws_[4];
        #pragma unroll
        for (int q = 0; q < 4; ++q) {
            wd[q]  = *reinterpret_cast<const float2*>(&Wm1[(size_t)(k + q) * M1 + j]);
            ws_[q] = *reinterpret_cast<const float2*>(&Wm1[(size_t)(H + k + q) * M1 + j]);
        }
        #pragma unroll
        for (int e = 0; e < 8; ++e) {
            const float* xr = &sX[e0 + e][k];
            #pragma unroll
            for (int q = 0; q < 4; ++q) {
                float xv = xr[q];
                ad[e].x  = fmaf(xv, wd[q].x,  ad[e].x);
                ad[e].y  = fmaf(xv, wd[q].y,  ad[e].y);
                as2[e].x = fmaf(xv, ws_[q].x, as2[e].x);
                as2[e].y = fmaf(xv, ws_[q].y, as2[e].y);
            }
        }
    }
    const float2 b = *reinterpret_cast<const float2*>(&bm1[j]);
    #pragma unroll
    for (int e = 0; e < 8; ++e) {
        int node = nbase + e0 + e;
        if (node < NN) {
            *reinterpret_cast<float2*>(&Pd[(size_t)node * H + j]) =
                make_float2(ad[e].x + b.x, ad[e].y + b.y);
            *reinterpret_cast<float2*>(&Ps[(size_t)node * H + j]) = as2[e];
        }
    }
}

// ---------------------------------------------------------------------------
// K2: fused edge pipeline with split-bf16 MFMA for the two big GEMMs.
//     64 edges/block, 256 threads (4 waves).
// ---------------------------------------------------------------------------
__global__ __launch_bounds__(256, 2) void edge_kernel(
    const float* __restrict__ edge_attr, const int* __restrict__ edge_index,
    const float* __restrict__ We1, const float* __restrict__ be1,
    const float* __restrict__ We2, const float* __restrict__ be2,
    const float* __restrict__ bm2,
    const __bf16* __restrict__ w1h, const __bf16* __restrict__ w1l,
    const __bf16* __restrict__ w2h, const __bf16* __restrict__ w2l,
    const float* __restrict__ Pd, const float* __restrict__ Ps,
    float* __restrict__ agg2, float* __restrict__ deg)
{
    __shared__ __align__(16) float  sA[TE][ED];            // 8 KB  edge_attr
    __shared__ __align__(16) float  sEH[TE][EHD];          // 8 KB  encoder hidden
    __shared__ __align__(16) __bf16 sEAh[2 * 2 * 64 * 8];  // 4 KB  ea frags [mt][s][lane][e]
    __shared__ __align__(16) __bf16 sEAl[2 * 2 * 64 * 8];  // 4 KB
    // union: sP fp32 [64][128] (staged Pd[dst]+Ps[src], C-init of phase4)
    //     -> sH1h/sH1l packed bf16 frags [mt(2)][s(8)][lane(64)][e(8)]
    __shared__ __align__(16) float  sU[TE * M1];           // 32 KB
    __shared__ int sSrc[TE], sDst[TE];

    float*  sP   = sU;
    __bf16* sH1h = reinterpret_cast<__bf16*>(sU);
    __bf16* sH1l = sH1h + 8192;

    const int t  = threadIdx.x;
    const int wv = t >> 6;
    const int ln = t & 63;
    const size_t ebase = (size_t)blockIdx.x * TE;

    if (t < TE) {
        sSrc[t] = edge_index[ebase + t];        // row 0 = src
        sDst[t] = edge_index[EE + ebase + t];   // row 1 = dst
    }
    {   // edge_attr tile: 64*32 fp32 = 512 float4, coalesced
        const float4* ga = reinterpret_cast<const float4*>(edge_attr + ebase * ED);
        float4* la = reinterpret_cast<float4*>(&sA[0][0]);
        la[t]       = ga[t];
        la[t + 256] = ga[t + 256];
    }
    __syncthreads();

    // --- issue Pd/Ps gathers EARLY; latency hides under encoder compute ---
    float4 gpd[8], gps[8];
    #pragma unroll
    for (int p = 0; p < 8; ++p) {
        int slot = t + p * 256;                 // 2048 float4-slots = [64 rows][32 f4]
        int row = slot >> 5, c = slot & 31;
        gpd[p] = reinterpret_cast<const float4*>(Pd + (size_t)sDst[row] * H)[c];
        gps[p] = reinterpret_cast<const float4*>(Ps + (size_t)sSrc[row] * H)[c];
    }

    // --- encoder layer 1: sEH = relu(sA @ We1 + be1)  (VALU, fp32) ---
    {
        const int j  = t & 31;
        const int e0 = (t >> 5) * 8;
        float acc[8] = {};
        for (int k = 0; k < ED; k += 4) {
            float w0 = We1[(k    ) * EHD + j];
            float w1 = We1[(k + 1) * EHD + j];
            float w2 = We1[(k + 2) * EHD + j];
            float w3 = We1[(k + 3) * EHD + j];
            #pragma unroll
            for (int e = 0; e < 8; ++e) {
                float4 a = *reinterpret_cast<const float4*>(&sA[e0 + e][k]);  // broadcast
                acc[e] = fmaf(a.w, w3, fmaf(a.z, w2, fmaf(a.y, w1, fmaf(a.x, w0, acc[e]))));
            }
        }
        const float b = be1[j];
        #pragma unroll
        for (int e = 0; e < 8; ++e) sEH[e0 + e][j] = fmaxf(acc[e] + b, 0.f);
    }
    __syncthreads();

    // --- land the gathers: sP = Pd[dst] + Ps[src] ---
    #pragma unroll
    for (int p = 0; p < 8; ++p) {
        int slot = t + p * 256;
        float4 a = gpd[p], b = gps[p];
        reinterpret_cast<float4*>(sP)[slot] =
            make_float4(a.x + b.x, a.y + b.y, a.z + b.z, a.w + b.w);
    }

    // --- encoder layer 2: ea = sEH @ We2 + be2, split into bf16 hi/lo frags ---
    {
        const int j  = t & 31;
        const int e0 = (t >> 5) * 8;
        float acc[8] = {};
        for (int k = 0; k < EHD; k += 4) {
            float w0 = We2[(k    ) * EHD + j];
            float w1 = We2[(k + 1) * EHD + j];
            float w2 = We2[(k + 2) * EHD + j];
            float w3 = We2[(k + 3) * EHD + j];
            #pragma unroll
            for (int e = 0; e < 8; ++e) {
                float4 a = *reinterpret_cast<const float4*>(&sEH[e0 + e][k]);  // broadcast
                acc[e] = fmaf(a.w, w3, fmaf(a.z, w2, fmaf(a.y, w1, fmaf(a.x, w0, acc[e]))));
            }
        }
        const float b = be2[j];
        const int s = j >> 4, laneHi = (j >> 3) & 1, e8 = j & 7;
        #pragma unroll
        for (int ee = 0; ee < 8; ++ee) {
            int m  = e0 + ee;
            int mt = m >> 5;
            int off = ((mt * 2 + s) * 64 + ((m & 31) + 32 * laneHi)) * 8 + e8;
            float v = acc[ee] + b;
            __bf16 hi = (__bf16)v;
            sEAh[off] = hi;
            sEAl[off] = (__bf16)(v - (float)hi);
        }
    }
    __syncthreads();   // sEA frags + sP ready

    // --- phase 4 (MFMA): h1 = relu(sP + EA @ Wm1e) ; M=64,N=128,K=32 ---
    // wave w: mt = w>>1, n-tiles {2*(w&1), 2*(w&1)+1}
    const int mt  = wv >> 1;
    const int ntb = (wv & 1) * 2;
    f32x16 acc0, acc1;
    {
        const int ccol  = ntb * 32 + (ln & 31);
        const int crow0 = mt * 32 + (ln >> 5) * 4;
        #pragma unroll
        for (int q = 0; q < 16; ++q) {
            int row = crow0 + (q & 3) + 8 * (q >> 2);
            acc0[q] = sP[row * M1 + ccol];
            acc1[q] = sP[row * M1 + ccol + 32];
        }
        #pragma unroll
        for (int s = 0; s < 2; ++s) {
            bf16x8 ah = *reinterpret_cast<const bf16x8*>(&sEAh[((mt * 2 + s) * 64 + ln) * 8]);
            bf16x8 al = *reinterpret_cast<const bf16x8*>(&sEAl[((mt * 2 + s) * 64 + ln) * 8]);
            #pragma unroll
            for (int tt = 0; tt < 2; ++tt) {
                int nt = ntb + tt;
                bf16x8 bh = *reinterpret_cast<const bf16x8*>(&w1h[((nt * 2 + s) * 64 + ln) * 8]);
                bf16x8 bl = *reinterpret_cast<const bf16x8*>(&w1l[((nt * 2 + s) * 64 + ln) * 8]);
                f32x16& A = tt ? acc1 : acc0;
                A = MFMA(ah, bh, A);
                A = MFMA(ah, bl, A);
                A = MFMA(al, bh, A);
            }
        }
    }
    __syncthreads();   // every wave done reading sP -> safe to overwrite with sH1

    // --- relu + split h1 into packed bf16 frags (phase5 A-operand) ---
    {
        #pragma unroll
        for (int tt = 0; tt < 2; ++tt) {
            const int col = (ntb + tt) * 32 + (ln & 31);   // k-dim of phase5
            const int s = col >> 4, laneHi = (col >> 3) & 1, e8 = col & 7;
            const f32x16& A = tt ? acc1 : acc0;
            #pragma unroll
            for (int q = 0; q < 16; ++q) {
                int row = mt * 32 + (ln >> 5) * 4 + (q & 3) + 8 * (q >> 2);
                int off = ((mt * 8 + s) * 64 + ((row & 31) + 32 * laneHi)) * 8 + e8;
                float v = fmaxf(A[q], 0.f);
                __bf16 hi = (__bf16)v;
                sH1h[off] = hi;
                sH1l[off] = (__bf16)(v - (float)hi);
            }
        }
    }
    __syncthreads();

    // --- phase 5 (MFMA): h2 = relu(h1 @ Wm2 + bm2); scatter-add ---
    // wave w: tile (pm = w>>1, nt = w&1); M=64,N=64,K=128
    {
        const int pm = wv >> 1;
        const int nt = wv & 1;
        const int col = nt * 32 + (ln & 31);
        const float bias = bm2[col];
        f32x16 acc;
        #pragma unroll
        for (int q = 0; q < 16; ++q) acc[q] = bias;
        #pragma unroll
        for (int s = 0; s < 8; ++s) {
            bf16x8 ah = *reinterpret_cast<const bf16x8*>(&sH1h[((pm * 8 + s) * 64 + ln) * 8]);
            bf16x8 al = *reinterpret_cast<const bf16x8*>(&sH1l[((pm * 8 + s) * 64 + ln) * 8]);
            bf16x8 bh = *reinterpret_cast<const bf16x8*>(&w2h[((nt * 8 + s) * 64 + ln) * 8]);
            bf16x8 bl = *reinterpret_cast<const bf16x8*>(&w2l[((nt * 8 + s) * 64 + ln) * 8]);
            acc = MFMA(ah, bh, acc);
            acc = MFMA(ah, bl, acc);
            acc = MFMA(al, bh, acc);
        }
        #pragma unroll
        for (int q = 0; q < 16; ++q) {
            int row = pm * 32 + (ln >> 5) * 4 + (q & 3) + 8 * (q >> 2);
            float v = fmaxf(acc[q], 0.f);
            atomicAdd(agg2 + (size_t)sDst[row] * M2 + col, v);
        }
    }
    if (t < TE) atomicAdd(deg + sDst[t], 1.0f);
}

// ---------------------------------------------------------------------------
// K3: m = agg2@Wm3 + deg*bm3 ; GRU(m, x) ; BN(eval) ; +x
//     (8 nodes/thread per pass -> halved weight re-reads vs R0)
// ---------------------------------------------------------------------------
__global__ __launch_bounds__(256) void node_kernel(
    const float* __restrict__ x, const float* __restrict__ agg2,
    const float* __restrict__ deg,
    const float* __restrict__ Wm3, const float* __restrict__ bm3,
    const float* __restrict__ Wih, const float* __restrict__ bih,
    const float* __restrict__ Whh, const float* __restrict__ bhh,
    const float* __restrict__ gamma, const float* __restrict__ beta,
    const float* __restrict__ rmean, const float* __restrict__ rvar,
    float* __restrict__ out)
{
    __shared__ __align__(16) float sX[TN][H];
    __shared__ __align__(16) float sG[TN][M2];
    __shared__ __align__(16) float sM[TN][H];
    __shared__ float sDeg[TN];

    const int t = threadIdx.x;
    const int nbase = blockIdx.x * TN;

    #pragma unroll
    for (int p = 0; p < 4; ++p) {
        int idx = t + p * 256;
        int row = idx >> 5, col = idx & 31;
        int node = nbase + row; if (node >= NN) node = NN - 1;
        reinterpret_cast<float4*>(&sX[row][0])[col] =
            reinterpret_cast<const float4*>(x + (size_t)node * H)[col];
    }
    #pragma unroll
    for (int p = 0; p < 2; ++p) {
        int idx = t + p * 256;
        int row = idx >> 4, col = idx & 15;
        int node = nbase + row; if (node >= NN) node = NN - 1;
        reinterpret_cast<float4*>(&sG[row][0])[col] =
            reinterpret_cast<const float4*>(agg2 + (size_t)node * M2)[col];
    }
    if (t < TN) {
        int node = nbase + t; if (node >= NN) node = NN - 1;
        sDeg[t] = deg[node];
    }
    __syncthreads();

    // m = sG @ Wm3 + deg * bm3   -> sM
    {
        const int j  = (t & 63) * 2;
        const int e0 = (t >> 6) * 8;
        float2 acc[8];
        #pragma unroll
        for (int e = 0; e < 8; ++e) acc[e] = make_float2(0.f, 0.f);
        for (int k = 0; k < M2; k += 4) {
            float2 w[4];
            #pragma unroll
            for (int q = 0; q < 4; ++q)
                w[q] = *reinterpret_cast<const float2*>(&Wm3[(size_t)(k + q) * H + j]);
            #pragma unroll
            for (int e = 0; e < 8; ++e) {
                const float* gr = &sG[e0 + e][k];
                #pragma unroll
                for (int q = 0; q < 4; ++q) {
                    acc[e].x = fmaf(gr[q], w[q].x, acc[e].x);
                    acc[e].y = fmaf(gr[q], w[q].y, acc[e].y);
                }
            }
        }
        const float2 b = *reinterpret_cast<const float2*>(&bm3[j]);
        #pragma unroll
        for (int e = 0; e < 8; ++e) {
            float d = sDeg[e0 + e];
            sM[e0 + e][j]     = fmaf(d, b.x, acc[e].x);
            sM[e0 + e][j + 1] = fmaf(d, b.y, acc[e].y);
        }
    }
    __syncthreads();

    // GRU + BN + residual: 2 passes x 8 nodes/thread
    {
        const int jc = t & 127;
        const int ng = t >> 7;
        const float bir = bih[jc], biz = bih[H + jc], bin_ = bih[2 * H + jc];
        const float bhr = bhh[jc], bhz = bhh[H + jc], bhn = bhh[2 * H + jc];
        const float scale = gamma[jc] * rsqrtf(rvar[jc] + BN_EPS);
        const float rm = rmean[jc], bt = beta[jc];
        for (int pass = 0; pass < 2; ++pass) {
            const int n0 = pass * 16 + ng * 8;
            float ir[8] = {}, iz[8] = {}, inn[8] = {};
            float hr[8] = {}, hz[8] = {}, hn[8] = {};
            for (int k = 0; k < H; k += 4) {
                float wir[4], wiz[4], win_[4], whr[4], whz[4], whn[4];
                #pragma unroll
                for (int q = 0; q < 4; ++q) {
                    const float* wi = Wih + (size_t)(k + q) * 3 * H;
                    const float* wh = Whh + (size_t)(k + q) * 3 * H;
                    wir[q] = wi[jc]; wiz[q] = wi[H + jc]; win_[q] = wi[2 * H + jc];
                    whr[q] = wh[jc]; whz[q] = wh[H + jc]; whn[q] = wh[2 * H + jc];
                }
                #pragma unroll
                for (int i = 0; i < 8; ++i) {
                    float4 mv = *reinterpret_cast<const float4*>(&sM[n0 + i][k]);  // broadcast
                    float4 xv = *reinterpret_cast<const float4*>(&sX[n0 + i][k]);  // broadcast
                    ir[i]  = fmaf(mv.x, wir[0],  fmaf(mv.y, wir[1],  fmaf(mv.z, wir[2],  fmaf(mv.w, wir[3],  ir[i]))));
                    iz[i]  = fmaf(mv.x, wiz[0],  fmaf(mv.y, wiz[1],  fmaf(mv.z, wiz[2],  fmaf(mv.w, wiz[3],  iz[i]))));
                    inn[i] = fmaf(mv.x, win_[0], fmaf(mv.y, win_[1], fmaf(mv.z, win_[2], fmaf(mv.w, win_[3], inn[i]))));
                    hr[i]  = fmaf(xv.x, whr[0],  fmaf(xv.y, whr[1],  fmaf(xv.z, whr[2],  fmaf(xv.w, whr[3],  hr[i]))));
                    hz[i]  = fmaf(xv.x, whz[0],  fmaf(xv.y, whz[1],  fmaf(xv.z, whz[2],  fmaf(xv.w, whz[3],  hz[i]))));
                    hn[i]  = fmaf(xv.x, whn[0],  fmaf(xv.y, whn[1],  fmaf(xv.z, whn[2],  fmaf(xv.w, whn[3],  hn[i]))));
                }
            }
            #pragma unroll
            for (int i = 0; i < 8; ++i) {
                int node = nbase + n0 + i;
                if (node < NN) {
                    float r  = 1.f / (1.f + expf(-(ir[i] + bir + hr[i] + bhr)));
                    float z  = 1.f / (1.f + expf(-(iz[i] + biz + hz[i] + bhz)));
                    float nn2 = tanhf(inn[i] + bin_ + r * (hn[i] + bhn));
                    float xv = sX[n0 + i][jc];
                    float h  = (1.f - z) * nn2 + z * xv;
                    float hb = (h - rm) * scale + bt;
                    out[(size_t)node * H + jc] = hb + xv;
                }
            }
        }
    }
}

// ---------------------------------------------------------------------------
extern "C" void kernel_launch(void* const* d_in, const int* in_sizes, int n_in,
                              void* d_out, int out_size, void* d_ws, size_t ws_size,
                              hipStream_t stream) {
    const float* x         = (const float*)d_in[0];
    const float* edge_attr = (const float*)d_in[1];
    const int*   edge_idx  = (const int*)d_in[2];
    const float* We1 = (const float*)d_in[3];
    const float* be1 = (const float*)d_in[4];
    const float* We2 = (const float*)d_in[5];
    const float* be2 = (const float*)d_in[6];
    const float* Wm1 = (const float*)d_in[7];
    const float* bm1 = (const float*)d_in[8];
    const float* Wm2 = (const float*)d_in[9];
    const float* bm2 = (const float*)d_in[10];
    const float* Wm3 = (const float*)d_in[11];
    const float* bm3 = (const float*)d_in[12];
    const float* Wih = (const float*)d_in[13];
    const float* bih = (const float*)d_in[14];
    const float* Whh = (const float*)d_in[15];
    const float* bhh = (const float*)d_in[16];
    const float* gamma = (const float*)d_in[17];
    const float* beta  = (const float*)d_in[18];
    const float* rmean = (const float*)d_in[19];
    const float* rvar  = (const float*)d_in[20];
    float* out = (float*)d_out;

    float* ws   = (float*)d_ws;
    float* Pd   = ws;                                 // [N,128]
    float* Ps   = ws + (size_t)NN * H;                // [N,128]
    float* agg2 = ws + (size_t)2 * NN * H;            // [N,64]
    float* deg  = agg2 + (size_t)NN * M2;             // [N]
    __bf16* wpack = reinterpret_cast<__bf16*>(deg + NN);
    __bf16* w1h = wpack;                              // 4096
    __bf16* w1l = wpack + 4096;
    __bf16* w2h = wpack + 8192;                       // 8192
    __bf16* w2l = wpack + 16384;

    hipMemsetAsync(agg2, 0, (size_t)NN * (M2 + 1) * sizeof(float), stream);

    pack_weights_kernel<<<32, 256, 0, stream>>>(Wm1, Wm2, w1h, w1l, w2h, w2l);
    proj_kernel<<<(NN + TN - 1) / TN, 256, 0, stream>>>(x, Wm1, bm1, Pd, Ps);
    edge_kernel<<<EE / TE, 256, 0, stream>>>(edge_attr, edge_idx,
                                             We1, be1, We2, be2, bm2,
                                             w1h, w1l, w2h, w2l,
                                             Pd, Ps, agg2, deg);
    node_kernel<<<(NN + TN - 1) / TN, 256, 0, stream>>>(x, agg2, deg,
                                                        Wm3, bm3, Wih, bih, Whh, bhh,
                                                        gamma, beta, rmean, rvar, out);
}

// Round 5
// 533.869 us; speedup vs baseline: 2.0481x; 1.4384x over previous
//
#include <hip/hip_runtime.h>
#include <math.h>

// Problem constants (from reference)
constexpr int NN = 50000;
constexpr int EE = 800000;
constexpr int H  = 128;
constexpr int ED = 32;
constexpr int EHD = 32;
constexpr int M1 = 128;
constexpr int M2 = 64;
constexpr float BN_EPS = 1e-5f;

constexpr int TE = 64;   // edges per block
constexpr int TN = 32;   // nodes per block

typedef __bf16 bf16x8 __attribute__((ext_vector_type(8)));
typedef float  f32x16 __attribute__((ext_vector_type(16)));

static __device__ __forceinline__ f32x16 MFMA(bf16x8 a, bf16x8 b, f32x16 c) {
    return __builtin_amdgcn_mfma_f32_32x32x16_bf16(a, b, c, 0, 0, 0);
}
static __device__ __forceinline__ void split2(float v, __bf16& h, __bf16& l) {
    h = (__bf16)v; l = (__bf16)(v - (float)h);
}

// ---------------------------------------------------------------------------
// K0: split weights into bf16 hi/lo pairs, pre-swizzled into MFMA B-fragment
// order: element (k, n) -> [((nt*NS + s)*64 + (n&31) + 32*((k>>3)&1))*8 + (k&7)]
// with s = (k>>4), nt = n>>5.
// ---------------------------------------------------------------------------
__global__ void pack_weights_kernel(
    const float* __restrict__ Wm1, const float* __restrict__ Wm2,
    const float* __restrict__ Wm3, const float* __restrict__ Wih,
    const float* __restrict__ Whh,
    __bf16* __restrict__ w1h, __bf16* __restrict__ w1l,
    __bf16* __restrict__ w2h, __bf16* __restrict__ w2l,
    __bf16* __restrict__ w3h, __bf16* __restrict__ w3l,
    __bf16* __restrict__ wph, __bf16* __restrict__ wpl,
    __bf16* __restrict__ wihh, __bf16* __restrict__ wihl,
    __bf16* __restrict__ whhh, __bf16* __restrict__ whhl)
{
    int t = blockIdx.x * blockDim.x + threadIdx.x;
    int e = t & 7, l = (t >> 3) & 63;
    if (t < 4096) {  // Wm1 edge part rows 256..287 (32x128): nt(4) x s(2)
        int s = (t >> 9) & 1, nt = (t >> 10) & 3;
        int k = s * 16 + (l >> 5) * 8 + e, n = nt * 32 + (l & 31);
        split2(Wm1[(size_t)(2 * H + k) * M1 + n], w1h[t], w1l[t]);
    }
    if (t < 8192) {  // Wm2 (128x64): nt(2) x s(8)
        int s = (t >> 9) & 7, nt = (t >> 12) & 1;
        int k = s * 16 + (l >> 5) * 8 + e, n = nt * 32 + (l & 31);
        split2(Wm2[(size_t)k * M2 + n], w2h[t], w2l[t]);
    }
    if (t < 8192) {  // Wm3 (64x128): nt(4) x s(4)
        int s = (t >> 9) & 3, nt = (t >> 11) & 3;
        int k = s * 16 + (l >> 5) * 8 + e, n = nt * 32 + (l & 31);
        split2(Wm3[(size_t)k * H + n], w3h[t], w3l[t]);
    }
    if (t < 32768) {  // Wp = [Wd | Ws] (128x256): nt(8) x s(8)
        int s = (t >> 9) & 7, nt = (t >> 12) & 7;
        int k = s * 16 + (l >> 5) * 8 + e, n = nt * 32 + (l & 31);
        float w = (n < 128) ? Wm1[(size_t)k * M1 + n]
                            : Wm1[(size_t)(H + k) * M1 + (n - 128)];
        split2(w, wph[t], wpl[t]);
    }
    if (t < 49152) {  // Wih (128x384): nt(12) x s(8)
        int s = (t >> 9) & 7, nt = t >> 12;
        int k = s * 16 + (l >> 5) * 8 + e, n = nt * 32 + (l & 31);
        split2(Wih[(size_t)k * 3 * H + n], wihh[t], wihl[t]);
    }
    if (t < 49152) {  // Whh (128x384): nt(12) x s(8)
        int s = (t >> 9) & 7, nt = t >> 12;
        int k = s * 16 + (l >> 5) * 8 + e, n = nt * 32 + (l & 31);
        split2(Whh[(size_t)k * 3 * H + n], whhh[t], whhl[t]);
    }
}

// ---------------------------------------------------------------------------
// K1: proj (MFMA, LDS-free): [Pd|Ps] = x @ [Wd|Ws] (+bm1 on Pd cols)
//     32 nodes/block, 4 waves; wave w owns n-tiles {2w, 2w+1} of 256 cols.
// ---------------------------------------------------------------------------
__global__ __launch_bounds__(256) void proj_kernel(
    const float* __restrict__ x,
    const __bf16* __restrict__ wph, const __bf16* __restrict__ wpl,
    const float* __restrict__ bm1,
    float* __restrict__ Pd, float* __restrict__ Ps)
{
    const int t = threadIdx.x, wv = t >> 6, ln = t & 63;
    const int nbase = blockIdx.x * TN;
    const int nodeA = min(nbase + (ln & 31), NN - 1);
    const int nt0 = wv * 2, nt1 = wv * 2 + 1;
    const int g0 = nt0 * 32 + (ln & 31), g1 = g0 + 32;

    const float b0 = (g0 < 128) ? bm1[g0] : 0.f;
    const float b1 = (g1 < 128) ? bm1[g1] : 0.f;
    f32x16 acc0, acc1;
    #pragma unroll
    for (int q = 0; q < 16; ++q) { acc0[q] = b0; acc1[q] = b1; }

    #pragma unroll
    for (int s = 0; s < 8; ++s) {
        const float* xp = x + (size_t)nodeA * H + s * 16 + (ln >> 5) * 8;
        float4 xa = *reinterpret_cast<const float4*>(xp);
        float4 xb = *reinterpret_cast<const float4*>(xp + 4);
        float v[8] = {xa.x, xa.y, xa.z, xa.w, xb.x, xb.y, xb.z, xb.w};
        bf16x8 ah, al;
        #pragma unroll
        for (int i = 0; i < 8; ++i) { __bf16 h; __bf16 lo; split2(v[i], h, lo); ah[i] = h; al[i] = lo; }
        bf16x8 b0h = *reinterpret_cast<const bf16x8*>(&wph[((nt0 * 8 + s) * 64 + ln) * 8]);
        bf16x8 b0l = *reinterpret_cast<const bf16x8*>(&wpl[((nt0 * 8 + s) * 64 + ln) * 8]);
        bf16x8 b1h = *reinterpret_cast<const bf16x8*>(&wph[((nt1 * 8 + s) * 64 + ln) * 8]);
        bf16x8 b1l = *reinterpret_cast<const bf16x8*>(&wpl[((nt1 * 8 + s) * 64 + ln) * 8]);
        acc0 = MFMA(ah, b0h, acc0); acc0 = MFMA(ah, b0l, acc0); acc0 = MFMA(al, b0h, acc0);
        acc1 = MFMA(ah, b1h, acc1); acc1 = MFMA(ah, b1l, acc1); acc1 = MFMA(al, b1h, acc1);
    }
    #pragma unroll
    for (int q = 0; q < 16; ++q) {
        int row = (q & 3) + 8 * (q >> 2) + 4 * (ln >> 5);
        int node = nbase + row;
        if (node < NN) {
            if (g0 < 128) Pd[(size_t)node * H + g0] = acc0[q];
            else          Ps[(size_t)node * H + (g0 - 128)] = acc0[q];
            if (g1 < 128) Pd[(size_t)node * H + g1] = acc1[q];
            else          Ps[(size_t)node * H + (g1 - 128)] = acc1[q];
        }
    }
}

// ---------------------------------------------------------------------------
// K2: fused edge pipeline, fully-overlaid 32KB LDS region:
//   early:  sA [64][32] (8K) | sEH [64][32] (8K) | sEAh (4K) | sEAl (4K) | 8K free
//   late:   sH1h (16K) | sH1l (16K)     (after barrier-protected phase switch)
// Total LDS ~33 KB -> 4 blocks/CU.
// ---------------------------------------------------------------------------
__global__ __launch_bounds__(256, 4) void edge_kernel(
    const float* __restrict__ edge_attr, const int* __restrict__ edge_index,
    const float* __restrict__ We1, const float* __restrict__ be1,
    const float* __restrict__ We2, const float* __restrict__ be2,
    const float* __restrict__ bm2,
    const __bf16* __restrict__ w1h, const __bf16* __restrict__ w1l,
    const __bf16* __restrict__ w2h, const __bf16* __restrict__ w2l,
    const float* __restrict__ Pd, const float* __restrict__ Ps,
    float* __restrict__ agg2, float* __restrict__ deg)
{
    __shared__ __align__(16) float sRegion[8192];          // 32 KB
    __shared__ int sSrc[TE], sDst[TE];

    float*  sA   = sRegion;                                   // floats [0,2048)
    float*  sEH  = sRegion + 2048;                            // floats [2048,4096)
    __bf16* sEAh = reinterpret_cast<__bf16*>(sRegion + 4096); // bytes [16384,20480)
    __bf16* sEAl = reinterpret_cast<__bf16*>(sRegion + 5120); // bytes [20480,24576)
    __bf16* sH1h = reinterpret_cast<__bf16*>(sRegion);        // bytes [0,16384)
    __bf16* sH1l = reinterpret_cast<__bf16*>(sRegion) + 8192; // bytes [16384,32768)

    const int t  = threadIdx.x;
    const int wv = t >> 6;
    const int ln = t & 63;
    const size_t ebase = (size_t)blockIdx.x * TE;

    if (t < TE) {
        sSrc[t] = edge_index[ebase + t];        // row 0 = src
        sDst[t] = edge_index[EE + ebase + t];   // row 1 = dst
    }
    {   // edge_attr tile: 64*32 fp32 = 512 float4, coalesced
        const float4* ga = reinterpret_cast<const float4*>(edge_attr + ebase * ED);
        float4* la = reinterpret_cast<float4*>(sA);
        la[t]       = ga[t];
        la[t + 256] = ga[t + 256];
    }
    __syncthreads();

    // --- early-issue C-init gathers (T14): Pd[dst]+Ps[src] -> accumulators.
    //     Latency hides under encoder layers 1+2.
    const int mt  = wv >> 1;
    const int ntb = (wv & 1) * 2;
    const int ccol = ntb * 32 + (ln & 31);
    const int rb   = mt * 32 + (ln >> 5) * 4;
    f32x16 acc0, acc1;
    #pragma unroll
    for (int q = 0; q < 16; ++q) {
        int row = rb + (q & 3) + 8 * (q >> 2);
        int dn = sDst[row], sn = sSrc[row];
        const float* pd = Pd + (size_t)dn * H + ccol;
        const float* ps = Ps + (size_t)sn * H + ccol;
        acc0[q] = pd[0]  + ps[0];
        acc1[q] = pd[32] + ps[32];
    }

    // --- encoder layer 1: sEH = relu(sA @ We1 + be1) (disjoint from sA) ---
    {
        const int j  = t & 31;
        const int e0 = (t >> 5) * 8;
        float acc[8] = {};
        for (int k = 0; k < ED; k += 4) {
            float w0 = We1[(k    ) * EHD + j];
            float w1 = We1[(k + 1) * EHD + j];
            float w2 = We1[(k + 2) * EHD + j];
            float w3 = We1[(k + 3) * EHD + j];
            #pragma unroll
            for (int e = 0; e < 8; ++e) {
                float4 a = *reinterpret_cast<const float4*>(&sA[(e0 + e) * ED + k]);
                acc[e] = fmaf(a.w, w3, fmaf(a.z, w2, fmaf(a.y, w1, fmaf(a.x, w0, acc[e]))));
            }
        }
        const float b = be1[j];
        #pragma unroll
        for (int e = 0; e < 8; ++e) sEH[(e0 + e) * EHD + j] = fmaxf(acc[e] + b, 0.f);
    }
    __syncthreads();

    // --- encoder layer 2: ea = sEH @ We2 + be2 -> bf16 hi/lo frags (disjoint) ---
    {
        const int j  = t & 31;
        const int e0 = (t >> 5) * 8;
        float acc[8] = {};
        for (int k = 0; k < EHD; k += 4) {
            float w0 = We2[(k    ) * EHD + j];
            float w1 = We2[(k + 1) * EHD + j];
            float w2 = We2[(k + 2) * EHD + j];
            float w3 = We2[(k + 3) * EHD + j];
            #pragma unroll
            for (int e = 0; e < 8; ++e) {
                float4 a = *reinterpret_cast<const float4*>(&sEH[(e0 + e) * EHD + k]);
                acc[e] = fmaf(a.w, w3, fmaf(a.z, w2, fmaf(a.y, w1, fmaf(a.x, w0, acc[e]))));
            }
        }
        const float b = be2[j];
        const int s = j >> 4, laneHi = (j >> 3) & 1, e8 = j & 7;
        #pragma unroll
        for (int ee = 0; ee < 8; ++ee) {
            int m  = e0 + ee;
            int mtile = m >> 5;
            int off = ((mtile * 2 + s) * 64 + ((m & 31) + 32 * laneHi)) * 8 + e8;
            split2(acc[ee] + b, sEAh[off], sEAl[off]);
        }
    }
    __syncthreads();   // sEA frags ready

    // --- phase 4 (MFMA): h1 = relu(C + EA @ Wm1e); M=64,N=128,K=32 ---
    {
        #pragma unroll
        for (int s = 0; s < 2; ++s) {
            bf16x8 ah = *reinterpret_cast<const bf16x8*>(&sEAh[((mt * 2 + s) * 64 + ln) * 8]);
            bf16x8 al = *reinterpret_cast<const bf16x8*>(&sEAl[((mt * 2 + s) * 64 + ln) * 8]);
            #pragma unroll
            for (int tt = 0; tt < 2; ++tt) {
                int nt = ntb + tt;
                bf16x8 bh = *reinterpret_cast<const bf16x8*>(&w1h[((nt * 2 + s) * 64 + ln) * 8]);
                bf16x8 bl = *reinterpret_cast<const bf16x8*>(&w1l[((nt * 2 + s) * 64 + ln) * 8]);
                f32x16& A = tt ? acc1 : acc0;
                A = MFMA(ah, bh, A);
                A = MFMA(ah, bl, A);
                A = MFMA(al, bh, A);
            }
        }
    }
    __syncthreads();   // ALL waves done reading sEA -> region may be overwritten

    // --- relu + split h1 into packed bf16 frags (overlays whole region) ---
    {
        #pragma unroll
        for (int tt = 0; tt < 2; ++tt) {
            const int col = (ntb + tt) * 32 + (ln & 31);   // k-dim of phase5
            const int s = col >> 4, laneHi = (col >> 3) & 1, e8 = col & 7;
            const f32x16& A = tt ? acc1 : acc0;
            #pragma unroll
            for (int q = 0; q < 16; ++q) {
                int row = mt * 32 + (ln >> 5) * 4 + (q & 3) + 8 * (q >> 2);
                int off = ((mt * 8 + s) * 64 + ((row & 31) + 32 * laneHi)) * 8 + e8;
                split2(fmaxf(A[q], 0.f), sH1h[off], sH1l[off]);
            }
        }
    }
    __syncthreads();

    // --- phase 5 (MFMA): h2 = relu(h1 @ Wm2 + bm2); scatter-add ---
    {
        const int pm = wv >> 1;
        const int nt = wv & 1;
        const int col = nt * 32 + (ln & 31);
        const float bias = bm2[col];
        f32x16 acc;
        #pragma unroll
        for (int q = 0; q < 16; ++q) acc[q] = bias;
        #pragma unroll
        for (int s = 0; s < 8; ++s) {
            bf16x8 ah = *reinterpret_cast<const bf16x8*>(&sH1h[((pm * 8 + s) * 64 + ln) * 8]);
            bf16x8 al = *reinterpret_cast<const bf16x8*>(&sH1l[((pm * 8 + s) * 64 + ln) * 8]);
            bf16x8 bh = *reinterpret_cast<const bf16x8*>(&w2h[((nt * 8 + s) * 64 + ln) * 8]);
            bf16x8 bl = *reinterpret_cast<const bf16x8*>(&w2l[((nt * 8 + s) * 64 + ln) * 8]);
            acc = MFMA(ah, bh, acc);
            acc = MFMA(ah, bl, acc);
            acc = MFMA(al, bh, acc);
        }
        #pragma unroll
        for (int q = 0; q < 16; ++q) {
            int row = pm * 32 + (ln >> 5) * 4 + (q & 3) + 8 * (q >> 2);
            float v = fmaxf(acc[q], 0.f);
            atomicAdd(agg2 + (size_t)sDst[row] * M2 + col, v);
        }
    }
    if (t < TE) atomicAdd(deg + sDst[t], 1.0f);
}

// ---------------------------------------------------------------------------
// gate GEMM helper: acc = bias + A(frags in LDS) @ B(packed global), K=128
// ---------------------------------------------------------------------------
static __device__ __forceinline__ f32x16 gemm_gate(
    const __bf16* __restrict__ sAh, const __bf16* __restrict__ sAl,
    const __bf16* __restrict__ bph, const __bf16* __restrict__ bpl,
    int nt, int ln, float bias)
{
    f32x16 acc;
    #pragma unroll
    for (int q = 0; q < 16; ++q) acc[q] = bias;
    #pragma unroll
    for (int s = 0; s < 8; ++s) {
        bf16x8 ah = *reinterpret_cast<const bf16x8*>(&sAh[(s * 64 + ln) * 8]);
        bf16x8 al = *reinterpret_cast<const bf16x8*>(&sAl[(s * 64 + ln) * 8]);
        bf16x8 bh = *reinterpret_cast<const bf16x8*>(&bph[((nt * 8 + s) * 64 + ln) * 8]);
        bf16x8 bl = *reinterpret_cast<const bf16x8*>(&bpl[((nt * 8 + s) * 64 + ln) * 8]);
        acc = MFMA(ah, bh, acc);
        acc = MFMA(ah, bl, acc);
        acc = MFMA(al, bh, acc);
    }
    return acc;
}

// ---------------------------------------------------------------------------
// K3: node kernel (MFMA): m = agg2@Wm3 + deg*bm3; gi = m@Wih; gh = x@Whh;
//     GRU + BN + residual fully in-register (wave owns same 32-col slice of
//     r, z, n gates). 32 nodes/block, 4 waves.
// ---------------------------------------------------------------------------
__global__ __launch_bounds__(256, 4) void node_kernel(
    const float* __restrict__ x, const float* __restrict__ agg2,
    const float* __restrict__ deg,
    const __bf16* __restrict__ w3h, const __bf16* __restrict__ w3l,
    const float* __restrict__ bm3,
    const __bf16* __restrict__ wihh, const __bf16* __restrict__ wihl,
    const float* __restrict__ bih,
    const __bf16* __restrict__ whhh, const __bf16* __restrict__ whhl,
    const float* __restrict__ bhh,
    const float* __restrict__ gamma, const float* __restrict__ beta,
    const float* __restrict__ rmean, const float* __restrict__ rvar,
    float* __restrict__ out)
{
    __shared__ __align__(16) __bf16 sXfh[4096], sXfl[4096];  // x frags [s8][64][8]
    __shared__ __align__(16) __bf16 sMfh[4096], sMfl[4096];  // m frags [s8][64][8]
    __shared__ float sDeg[TN];

    const int t = threadIdx.x, wv = t >> 6, ln = t & 63;
    const int nbase = blockIdx.x * TN;

    if (t < TN) sDeg[t] = deg[min(nbase + t, NN - 1)];

    // --- phase 1: x tile -> bf16 hi/lo frags in LDS (512 groups of 8 cols) ---
    #pragma unroll
    for (int p = 0; p < 2; ++p) {
        int grp = t + p * 256;                  // [row(32)][c8(16)]
        int row = grp >> 4, c8 = grp & 15;
        int k0 = c8 * 8;
        int node = min(nbase + row, NN - 1);
        const float* xp = x + (size_t)node * H + k0;
        float4 xa = *reinterpret_cast<const float4*>(xp);
        float4 xb = *reinterpret_cast<const float4*>(xp + 4);
        float v[8] = {xa.x, xa.y, xa.z, xa.w, xb.x, xb.y, xb.z, xb.w};
        bf16x8 h8, l8;
        #pragma unroll
        for (int i = 0; i < 8; ++i) { __bf16 h; __bf16 lo; split2(v[i], h, lo); h8[i] = h; l8[i] = lo; }
        int off = ((k0 >> 4) * 64 + row + 32 * ((k0 >> 3) & 1)) * 8;
        *reinterpret_cast<bf16x8*>(&sXfh[off]) = h8;
        *reinterpret_cast<bf16x8*>(&sXfl[off]) = l8;
    }
    __syncthreads();

    // --- phase 2: m = agg2 @ Wm3 + deg*bm3 -> frags in LDS ---
    {
        const int col = wv * 32 + (ln & 31);
        const int nodeA = min(nbase + (ln & 31), NN - 1);
        f32x16 acc;
        #pragma unroll
        for (int q = 0; q < 16; ++q) acc[q] = 0.f;
        #pragma unroll
        for (int s = 0; s < 4; ++s) {
            const float* ap = agg2 + (size_t)nodeA * M2 + s * 16 + (ln >> 5) * 8;
            float4 aa = *reinterpret_cast<const float4*>(ap);
            float4 ab = *reinterpret_cast<const float4*>(ap + 4);
            float v[8] = {aa.x, aa.y, aa.z, aa.w, ab.x, ab.y, ab.z, ab.w};
            bf16x8 ah, al;
            #pragma unroll
            for (int i = 0; i < 8; ++i) { __bf16 h; __bf16 lo; split2(v[i], h, lo); ah[i] = h; al[i] = lo; }
            bf16x8 bh = *reinterpret_cast<const bf16x8*>(&w3h[((wv * 4 + s) * 64 + ln) * 8]);
            bf16x8 bl = *reinterpret_cast<const bf16x8*>(&w3l[((wv * 4 + s) * 64 + ln) * 8]);
            acc = MFMA(ah, bh, acc);
            acc = MFMA(ah, bl, acc);
            acc = MFMA(al, bh, acc);
        }
        const float bm3v = bm3[col];
        const int sM = col >> 4, lHi = 32 * ((col >> 3) & 1), e8 = col & 7;
        #pragma unroll
        for (int q = 0; q < 16; ++q) {
            int row = (q & 3) + 8 * (q >> 2) + 4 * (ln >> 5);
            float mval = acc[q] + sDeg[row] * bm3v;
            int off = (sM * 64 + row + lHi) * 8 + e8;
            split2(mval, sMfh[off], sMfl[off]);
        }
    }
    __syncthreads();

    // --- phase 3: gates + GRU + BN + residual, all in-register per wave ---
    {
        const int col0 = wv * 32 + (ln & 31);
        f32x16 gi, gh, r_, z_;
        gi = gemm_gate(sMfh, sMfl, wihh, wihl, 0 + wv, ln, bih[col0]);
        gh = gemm_gate(sXfh, sXfl, whhh, whhl, 0 + wv, ln, bhh[col0]);
        #pragma unroll
        for (int q = 0; q < 16; ++q) r_[q] = 1.f / (1.f + expf(-(gi[q] + gh[q])));
        gi = gemm_gate(sMfh, sMfl, wihh, wihl, 4 + wv, ln, bih[H + col0]);
        gh = gemm_gate(sXfh, sXfl, whhh, whhl, 4 + wv, ln, bhh[H + col0]);
        #pragma unroll
        for (int q = 0; q < 16; ++q) z_[q] = 1.f / (1.f + expf(-(gi[q] + gh[q])));
        gi = gemm_gate(sMfh, sMfl, wihh, wihl, 8 + wv, ln, bih[2 * H + col0]);
        gh = gemm_gate(sXfh, sXfl, whhh, whhl, 8 + wv, ln, bhh[2 * H + col0]);

        const float scale = gamma[col0] * rsqrtf(rvar[col0] + BN_EPS);
        const float rm = rmean[col0], bt = beta[col0];
        #pragma unroll
        for (int q = 0; q < 16; ++q) {
            int row = (q & 3) + 8 * (q >> 2) + 4 * (ln >> 5);
            int node = nbase + row;
            if (node < NN) {
                float xv = x[(size_t)node * H + col0];
                float n  = tanhf(gi[q] + r_[q] * gh[q]);
                float h  = (1.f - z_[q]) * n + z_[q] * xv;
                out[(size_t)node * H + col0] = (h - rm) * scale + bt + xv;
            }
        }
    }
}

// ---------------------------------------------------------------------------
extern "C" void kernel_launch(void* const* d_in, const int* in_sizes, int n_in,
                              void* d_out, int out_size, void* d_ws, size_t ws_size,
                              hipStream_t stream) {
    const float* x         = (const float*)d_in[0];
    const float* edge_attr = (const float*)d_in[1];
    const int*   edge_idx  = (const int*)d_in[2];
    const float* We1 = (const float*)d_in[3];
    const float* be1 = (const float*)d_in[4];
    const float* We2 = (const float*)d_in[5];
    const float* be2 = (const float*)d_in[6];
    const float* Wm1 = (const float*)d_in[7];
    const float* bm1 = (const float*)d_in[8];
    const float* Wm2 = (const float*)d_in[9];
    const float* bm2 = (const float*)d_in[10];
    const float* Wm3 = (const float*)d_in[11];
    const float* bm3 = (const float*)d_in[12];
    const float* Wih = (const float*)d_in[13];
    const float* bih = (const float*)d_in[14];
    const float* Whh = (const float*)d_in[15];
    const float* bhh = (const float*)d_in[16];
    const float* gamma = (const float*)d_in[17];
    const float* beta  = (const float*)d_in[18];
    const float* rmean = (const float*)d_in[19];
    const float* rvar  = (const float*)d_in[20];
    float* out = (float*)d_out;

    float* ws   = (float*)d_ws;
    float* Pd   = ws;                                 // [N,128]
    float* Ps   = ws + (size_t)NN * H;                // [N,128]
    float* agg2 = ws + (size_t)2 * NN * H;            // [N,64]
    float* deg  = agg2 + (size_t)NN * M2;             // [N]
    __bf16* wp = reinterpret_cast<__bf16*>(deg + NN);
    __bf16* w1h = wp;               __bf16* w1l = w1h + 4096;
    __bf16* w2h = w1l + 4096;       __bf16* w2l = w2h + 8192;
    __bf16* w3h = w2l + 8192;       __bf16* w3l = w3h + 8192;
    __bf16* wph = w3l + 8192;       __bf16* wpl = wph + 32768;
    __bf16* wihh = wpl + 32768;     __bf16* wihl = wihh + 49152;
    __bf16* whhh = wihl + 49152;    __bf16* whhl = whhh + 49152;

    hipMemsetAsync(agg2, 0, (size_t)NN * (M2 + 1) * sizeof(float), stream);

    pack_weights_kernel<<<192, 256, 0, stream>>>(Wm1, Wm2, Wm3, Wih, Whh,
                                                 w1h, w1l, w2h, w2l, w3h, w3l,
                                                 wph, wpl, wihh, wihl, whhh, whhl);
    proj_kernel<<<(NN + TN - 1) / TN, 256, 0, stream>>>(x, wph, wpl, bm1, Pd, Ps);
    edge_kernel<<<EE / TE, 256, 0, stream>>>(edge_attr, edge_idx,
                                             We1, be1, We2, be2, bm2,
                                             w1h, w1l, w2h, w2l,
                                             Pd, Ps, agg2, deg);
    node_kernel<<<(NN + TN - 1) / TN, 256, 0, stream>>>(x, agg2, deg,
                                                        w3h, w3l, bm3,
                                                        wihh, wihl, bih,
                                                        whhh, whhl, bhh,
                                                        gamma, beta, rmean, rvar, out);
}